// Round 4
// baseline (95.902 us; speedup 1.0000x reference)
//
#include <hip/hip_runtime.h>
#include <math.h>

#define TWO_N 512
#define DM    256
#define NT    256

// ws layout (bytes):
//   Rp    : [512*512] float @ 0         -- distances, COLUMNS PERMUTED to t-sorted order
//   ts    : [512] float     @ 1048576   -- targets sorted ascending (stable)
//   inv   : [512] int       @ 1050624   -- inv[c] = sorted position of target c
//   accum : double          @ 1052672
//   count : uint            @ 1052680
#define OFF_TS   1048576
#define OFF_INV  1050624
#define OFF_ACC  1052672
#define OFF_CNT  1052680

#define ACC4(acc, A, B) { float _d;                      \
    _d = (A).x - (B).x; acc += _d * _d;                  \
    _d = (A).y - (B).y; acc += _d * _d;                  \
    _d = (A).z - (B).z; acc += _d * _d;                  \
    _d = (A).w - (B).w; acc += _d * _d; }

// Blocks 0..255: 32x32 distance tiles, written to Rp with columns scattered to
// their t-sorted positions (local rank-count gives inv for the 32 columns).
// Block 256: full rank-count sort of targets -> ts/inv global; zeroes accum/count.
__global__ __launch_bounds__(NT) void supcr_dist_sort(
    const float* __restrict__ E, const float* __restrict__ T,
    float* __restrict__ Rp, float* __restrict__ ts_g, int* __restrict__ inv_g,
    double* __restrict__ accum, unsigned int* __restrict__ count)
{
    const int bid = blockIdx.x;
    const int t   = threadIdx.x;

    __shared__ float tv[TWO_N];
    tv[t]       = T[t];
    tv[t + 256] = T[t + 256];
    __syncthreads();

    if (bid < 256) {
        __shared__ float4 As4[32 * 65];   // padded rows: bank-friendly
        __shared__ float4 Bs4[32 * 65];
        __shared__ int    cnt[32 * 9];    // [col][slice], padded
        __shared__ int    invc_s[32];

        const int it = bid >> 4, jt = bid & 15;

        // local rank-count for this tile's 32 columns (stable ties)
        {
            const int cl = t >> 3;          // 0..31 local col
            const int ss = t & 7;           // 0..7 slice
            const int c  = jt * 32 + cl;
            const float tc = tv[c];
            int n = 0;
            const int j0 = ss * 64;
            #pragma unroll 8
            for (int j = j0; j < j0 + 64; ++j) {
                const float tj = tv[j];
                n += (tj < tc) || (tj == tc && j < c);
            }
            cnt[cl * 9 + ss] = n;
        }

        // coalesced staging of A/B tiles
        const float4* __restrict__ E4 = reinterpret_cast<const float4*>(E);
        for (int idx = t; idx < 32 * 64; idx += NT) {
            const int row = idx >> 6, c4 = idx & 63;
            As4[row * 65 + c4] = E4[(it * 32 + row) * 64 + c4];
            Bs4[row * 65 + c4] = E4[(jt * 32 + row) * 64 + c4];
        }
        __syncthreads();

        if (t < 32) {
            int r = 0;
            #pragma unroll
            for (int ss = 0; ss < 8; ++ss) r += cnt[t * 9 + ss];
            invc_s[t] = r;
        }
        __syncthreads();

        const int ty = t >> 4, tx = t & 15;
        float a00 = 0.f, a01 = 0.f, a10 = 0.f, a11 = 0.f;
        #pragma unroll 8
        for (int k4 = 0; k4 < 64; ++k4) {
            const float4 a0 = As4[ty * 65 + k4];
            const float4 a1 = As4[(ty + 16) * 65 + k4];
            const float4 b0 = Bs4[tx * 65 + k4];
            const float4 b1 = Bs4[(tx + 16) * 65 + k4];
            ACC4(a00, a0, b0); ACC4(a01, a0, b1);
            ACC4(a10, a1, b0); ACC4(a11, a1, b1);
        }
        const int r0 = it * 32 + ty, r1 = r0 + 16;
        const int m0 = invc_s[tx],  m1 = invc_s[tx + 16];
        Rp[r0 * TWO_N + m0] = sqrtf(a00);
        Rp[r0 * TWO_N + m1] = sqrtf(a01);
        Rp[r1 * TWO_N + m0] = sqrtf(a10);
        Rp[r1 * TWO_N + m1] = sqrtf(a11);
    } else {
        // rank-count sort of all 512 targets (2 elems/thread)
        #pragma unroll
        for (int w = 0; w < 2; ++w) {
            const int c  = t + w * 256;
            const float tc = tv[c];
            int r = 0;
            #pragma unroll 8
            for (int j = 0; j < TWO_N; ++j) {
                const float tj = tv[j];
                r += (tj < tc) || (tj == tc && j < c);
            }
            ts_g[r]  = tc;
            inv_g[c] = r;
        }
        if (t == 0) { *accum = 0.0; *count = 0u; }
    }
}

// One block per row i. Coalesced Rp row; prefix sums in sorted order; per-m
// monotone searches give the contiguous {d < theta} interval; atomic finalize.
__global__ __launch_bounds__(NT) void supcr_rows(
    const float* __restrict__ T, const float* __restrict__ Rp,
    const float* __restrict__ ts_g, const int* __restrict__ inv_g,
    double* __restrict__ accum, unsigned int* __restrict__ count,
    float* __restrict__ out)
{
    const int i = blockIdx.x;
    const int t = threadIdx.x;

    __shared__ float  ts[TWO_N];
    __shared__ float  rv[TWO_N];    // Rp row (distances, sorted-col order)
    __shared__ float  P[TWO_N];     // inclusive prefix sums of s~
    __shared__ double red[NT];

    const int   mi = inv_g[i];
    const float ti = T[i];
    const float* __restrict__ row = Rp + (size_t)i * TWO_N;

    #pragma unroll
    for (int w = 0; w < 2; ++w) {
        const int m = t + w * 256;
        ts[m] = ts_g[m];
        const float r = row[m];
        rv[m] = r;
        P[m]  = (m == mi) ? 0.f : __expf(-r);
    }
    __syncthreads();

    // inclusive prefix sum (Hillis-Steele), 2 elements/thread
    for (int off = 1; off < TWO_N; off <<= 1) {
        const float v0 = (t >= off)       ? P[t - off]       : 0.f;
        const float v1 = (t + 256 >= off) ? P[t + 256 - off] : 0.f;
        __syncthreads();
        P[t]       += v0;
        P[t + 256] += v1;
        __syncthreads();
    }

    const float Stot = P[TWO_N - 1];

    float local = 0.f;
    #pragma unroll
    for (int w = 0; w < 2; ++w) {
        const int m = t + w * 256;
        if (m == mi) continue;
        const float theta = fabsf(ti - ts[m]);

        // left arm [0, mi]: d non-increasing; count leading d >= theta
        const int nl = mi + 1;
        int pos = 0;
        #pragma unroll
        for (int step = 512; step >= 1; step >>= 1) {
            const int np = pos + step;
            if (np <= nl && fabsf(ti - ts[np - 1]) >= theta) pos = np;
        }
        const int cl = nl - pos;             // left-arm count with d < theta

        // right arm [mi, 511]: d non-decreasing; count leading d < theta
        const int nr = TWO_N - mi;
        int pr = 0;
        #pragma unroll
        for (int step = 512; step >= 1; step >>= 1) {
            const int np = pr + step;
            if (np <= nr && fabsf(ti - ts[mi + np - 1]) < theta) pr = np;
        }

        const int L  = mi - cl + 1;
        const int Rr = mi + pr - 1;
        float inner = 0.f;
        if (Rr >= L) inner = P[Rr] - ((L > 0) ? P[L - 1] : 0.f);
        const float denom = Stot - inner;    // = sum over {d >= theta, j != i}
        local += -rv[m] - logf(denom);
    }

    red[t] = (double)local;
    __syncthreads();
    for (int off = NT / 2; off > 0; off >>= 1) {
        if (t < off) red[t] += red[t + off];
        __syncthreads();
    }
    if (t == 0) {
        const double part = red[0];
        const double old  = atomicAdd(accum, part);
        const unsigned int done = atomicAdd(count, 1u);
        if (done == TWO_N - 1) {
            out[0] = (float)(-(old + part) /
                             (double)((long long)TWO_N * (TWO_N - 1)));
        }
    }
}

extern "C" void kernel_launch(void* const* d_in, const int* in_sizes, int n_in,
                              void* d_out, int out_size, void* d_ws, size_t ws_size,
                              hipStream_t stream) {
    (void)in_sizes; (void)n_in; (void)out_size; (void)ws_size;
    const float* E = (const float*)d_in[0];   // [512,256] fp32
    const float* T = (const float*)d_in[1];   // [512]     fp32
    float* out = (float*)d_out;

    char* ws = (char*)d_ws;
    float*        Rp    = (float*)(ws);
    float*        ts_g  = (float*)(ws + OFF_TS);
    int*          inv_g = (int*)(ws + OFF_INV);
    double*       acc   = (double*)(ws + OFF_ACC);
    unsigned int* cnt   = (unsigned int*)(ws + OFF_CNT);

    supcr_dist_sort<<<257, NT, 0, stream>>>(E, T, Rp, ts_g, inv_g, acc, cnt);
    supcr_rows<<<TWO_N, NT, 0, stream>>>(T, Rp, ts_g, inv_g, acc, cnt, out);
}

// Round 5
// 89.231 us; speedup vs baseline: 1.0748x; 1.0748x over previous
//
#include <hip/hip_runtime.h>
#include <math.h>

#define TWO_N 512
#define DM    256
#define NT    256

// ws layout (bytes):
//   Rp    : [512*512] float @ 0         -- distances, COLUMNS PERMUTED to t-sorted order
//   ts    : [512] float     @ 1048576   -- targets sorted ascending (stable)
//   inv   : [512] int       @ 1050624   -- inv[c] = sorted position of target c
//   bsums : [512] double    @ 1052672
#define OFF_TS   1048576
#define OFF_INV  1050624
#define OFF_BSUM 1052672

#define ACC4(acc, A, B) { float _d;                      \
    _d = (A).x - (B).x; acc += _d * _d;                  \
    _d = (A).y - (B).y; acc += _d * _d;                  \
    _d = (A).z - (B).z; acc += _d * _d;                  \
    _d = (A).w - (B).w; acc += _d * _d; }

// Blocks 0..255: 32x32 distance tiles, written to Rp with columns scattered to
// their t-sorted positions (local rank-count gives inv for the 32 columns).
// Block 256: full rank-count sort of targets -> ts/inv global.
__global__ __launch_bounds__(NT) void supcr_dist_sort(
    const float* __restrict__ E, const float* __restrict__ T,
    float* __restrict__ Rp, float* __restrict__ ts_g, int* __restrict__ inv_g)
{
    const int bid = blockIdx.x;
    const int t   = threadIdx.x;

    __shared__ float tv[TWO_N];
    tv[t]       = T[t];
    tv[t + 256] = T[t + 256];
    __syncthreads();

    if (bid < 256) {
        __shared__ float4 As4[32 * 65];   // padded rows: bank-friendly
        __shared__ float4 Bs4[32 * 65];
        __shared__ int    cnt[32 * 9];    // [col][slice], padded
        __shared__ int    invc_s[32];

        const int it = bid >> 4, jt = bid & 15;

        // local rank-count for this tile's 32 columns (stable ties, global rank)
        {
            const int cl = t >> 3;          // 0..31 local col
            const int ss = t & 7;           // 0..7 slice
            const int c  = jt * 32 + cl;
            const float tc = tv[c];
            int n = 0;
            const int j0 = ss * 64;
            #pragma unroll 8
            for (int j = j0; j < j0 + 64; ++j) {
                const float tj = tv[j];
                n += (tj < tc) || (tj == tc && j < c);
            }
            cnt[cl * 9 + ss] = n;
        }

        // coalesced staging of A/B tiles
        const float4* __restrict__ E4 = reinterpret_cast<const float4*>(E);
        for (int idx = t; idx < 32 * 64; idx += NT) {
            const int row = idx >> 6, c4 = idx & 63;
            As4[row * 65 + c4] = E4[(it * 32 + row) * 64 + c4];
            Bs4[row * 65 + c4] = E4[(jt * 32 + row) * 64 + c4];
        }
        __syncthreads();

        if (t < 32) {
            int r = 0;
            #pragma unroll
            for (int ss = 0; ss < 8; ++ss) r += cnt[t * 9 + ss];
            invc_s[t] = r;
        }
        __syncthreads();

        const int ty = t >> 4, tx = t & 15;
        float a00 = 0.f, a01 = 0.f, a10 = 0.f, a11 = 0.f;
        #pragma unroll 8
        for (int k4 = 0; k4 < 64; ++k4) {
            const float4 a0 = As4[ty * 65 + k4];
            const float4 a1 = As4[(ty + 16) * 65 + k4];
            const float4 b0 = Bs4[tx * 65 + k4];
            const float4 b1 = Bs4[(tx + 16) * 65 + k4];
            ACC4(a00, a0, b0); ACC4(a01, a0, b1);
            ACC4(a10, a1, b0); ACC4(a11, a1, b1);
        }
        const int r0 = it * 32 + ty, r1 = r0 + 16;
        const int m0 = invc_s[tx],  m1 = invc_s[tx + 16];
        Rp[r0 * TWO_N + m0] = sqrtf(a00);
        Rp[r0 * TWO_N + m1] = sqrtf(a01);
        Rp[r1 * TWO_N + m0] = sqrtf(a10);
        Rp[r1 * TWO_N + m1] = sqrtf(a11);
    } else {
        // rank-count sort of all 512 targets (2 elems/thread)
        #pragma unroll
        for (int w = 0; w < 2; ++w) {
            const int c  = t + w * 256;
            const float tc = tv[c];
            int r = 0;
            #pragma unroll 8
            for (int j = 0; j < TWO_N; ++j) {
                const float tj = tv[j];
                r += (tj < tc) || (tj == tc && j < c);
            }
            ts_g[r]  = tc;
            inv_g[c] = r;
        }
    }
}

// One block per row i. Coalesced Rp row; prefix sums in sorted order; per-m
// monotone searches give the contiguous {d < theta} interval.
__global__ __launch_bounds__(NT) void supcr_rows(
    const float* __restrict__ T, const float* __restrict__ Rp,
    const float* __restrict__ ts_g, const int* __restrict__ inv_g,
    double* __restrict__ bsums)
{
    const int i = blockIdx.x;
    const int t = threadIdx.x;

    __shared__ float  ts[TWO_N];
    __shared__ float  rv[TWO_N];    // Rp row (distances, sorted-col order)
    __shared__ float  P[TWO_N];     // inclusive prefix sums of s~
    __shared__ double red[NT];

    const int   mi = inv_g[i];
    const float ti = T[i];
    const float* __restrict__ row = Rp + (size_t)i * TWO_N;

    #pragma unroll
    for (int w = 0; w < 2; ++w) {
        const int m = t + w * 256;
        ts[m] = ts_g[m];
        const float r = row[m];
        rv[m] = r;
        P[m]  = (m == mi) ? 0.f : __expf(-r);
    }
    __syncthreads();

    // inclusive prefix sum (Hillis-Steele), 2 elements/thread
    for (int off = 1; off < TWO_N; off <<= 1) {
        const float v0 = (t >= off)       ? P[t - off]       : 0.f;
        const float v1 = (t + 256 >= off) ? P[t + 256 - off] : 0.f;
        __syncthreads();
        P[t]       += v0;
        P[t + 256] += v1;
        __syncthreads();
    }

    const float Stot = P[TWO_N - 1];

    float local = 0.f;
    #pragma unroll
    for (int w = 0; w < 2; ++w) {
        const int m = t + w * 256;
        if (m == mi) continue;
        const float theta = fabsf(ti - ts[m]);

        // left arm [0, mi]: d non-increasing; count leading d >= theta
        const int nl = mi + 1;
        int pos = 0;
        #pragma unroll
        for (int step = 512; step >= 1; step >>= 1) {
            const int np = pos + step;
            if (np <= nl && fabsf(ti - ts[np - 1]) >= theta) pos = np;
        }
        const int cl = nl - pos;             // left-arm count with d < theta

        // right arm [mi, 511]: d non-decreasing; count leading d < theta
        const int nr = TWO_N - mi;
        int pr = 0;
        #pragma unroll
        for (int step = 512; step >= 1; step >>= 1) {
            const int np = pr + step;
            if (np <= nr && fabsf(ti - ts[mi + np - 1]) < theta) pr = np;
        }

        const int L  = mi - cl + 1;
        const int Rr = mi + pr - 1;
        float inner = 0.f;
        if (Rr >= L) inner = P[Rr] - ((L > 0) ? P[L - 1] : 0.f);
        const float denom = Stot - inner;    // = sum over {d >= theta, j != i}
        local += -rv[m] - logf(denom);
    }

    red[t] = (double)local;
    __syncthreads();
    for (int off = NT / 2; off > 0; off >>= 1) {
        if (t < off) red[t] += red[t + off];
        __syncthreads();
    }
    if (t == 0) bsums[i] = red[0];
}

__global__ __launch_bounds__(TWO_N) void supcr_finalize(
    const double* __restrict__ bsums, float* __restrict__ out)
{
    __shared__ double red[TWO_N];
    const int t = threadIdx.x;
    red[t] = bsums[t];
    __syncthreads();
    for (int off = TWO_N / 2; off > 0; off >>= 1) {
        if (t < off) red[t] += red[t + off];
        __syncthreads();
    }
    if (t == 0)
        out[0] = (float)(-red[0] / (double)((long long)TWO_N * (TWO_N - 1)));
}

extern "C" void kernel_launch(void* const* d_in, const int* in_sizes, int n_in,
                              void* d_out, int out_size, void* d_ws, size_t ws_size,
                              hipStream_t stream) {
    (void)in_sizes; (void)n_in; (void)out_size; (void)ws_size;
    const float* E = (const float*)d_in[0];   // [512,256] fp32
    const float* T = (const float*)d_in[1];   // [512]     fp32
    float* out = (float*)d_out;

    char* ws = (char*)d_ws;
    float*  Rp    = (float*)(ws);
    float*  ts_g  = (float*)(ws + OFF_TS);
    int*    inv_g = (int*)(ws + OFF_INV);
    double* bsums = (double*)(ws + OFF_BSUM);

    supcr_dist_sort<<<257, NT, 0, stream>>>(E, T, Rp, ts_g, inv_g);
    supcr_rows<<<TWO_N, NT, 0, stream>>>(T, Rp, ts_g, inv_g, bsums);
    supcr_finalize<<<1, TWO_N, 0, stream>>>(bsums, out);
}